// Round 7
// baseline (85.367 us; speedup 1.0000x reference)
//
#include <hip/hip_runtime.h>
#include <hip/hip_bf16.h>

#define N_S     64
#define C_CH    128
#define L_SEQ   1600
#define H_HEADS 8
#define HD      16
#define SEGN    64    // segments per (n,h)
#define SEGL    25    // elements per segment (64*25 = 1600)
#define PADW    136   // weight LDS row pad (bf16 elems)
#define PADT    72    // x/y tile LDS row pad (bf16 elems)

typedef __attribute__((ext_vector_type(8))) short bf16x8;
typedef __attribute__((ext_vector_type(4))) float f32x4;

__device__ inline unsigned short f2bf(float f) {
  return __builtin_bit_cast(unsigned short, __float2bfloat16(f));
}
__device__ inline float bflo(unsigned int u) { return __builtin_bit_cast(float, u << 16); }
__device__ inline float bfhi(unsigned int u) { return __builtin_bit_cast(float, u & 0xffff0000u); }
__device__ inline unsigned int pk(float a, float b) {
  return (unsigned int)f2bf(a) | ((unsigned int)f2bf(b) << 16);
}

// ---------------- K1: w2[n, c=16h+d, l] (bf16) = sum_c x[n,c,l]*Wa[16h+d][c] + ba ----------------
__global__ __launch_bounds__(256) void k_gemm1(const float* __restrict__ x,
                                               const float* __restrict__ Wa,
                                               const float* __restrict__ ba,
                                               unsigned short* __restrict__ w2) {
  __shared__ unsigned short was[128 * PADW];   // [o][c] rows
  __shared__ unsigned short xs[128 * PADT];    // [c][l] natural layout
  const int n = blockIdx.y;
  const int l0 = blockIdx.x * 64;
  const int t = threadIdx.x;
  const float* xn = x + (size_t)n * (C_CH * L_SEQ);

#pragma unroll
  for (int it = 0; it < 16; ++it) {
    int pos = it * 256 + t;
    int o = pos >> 5;
    int c4 = (pos & 31) << 2;
    float4 v = *reinterpret_cast<const float4*>(Wa + o * C_CH + c4);
    ushort4 u;
    u.x = f2bf(v.x); u.y = f2bf(v.y); u.z = f2bf(v.z); u.w = f2bf(v.w);
    *reinterpret_cast<ushort4*>(&was[o * PADW + c4]) = u;
  }
#pragma unroll
  for (int it = 0; it < 8; ++it) {
    int pos = it * 256 + t;
    int c = pos >> 4;
    int l4 = (pos & 15) << 2;
    float4 v = *reinterpret_cast<const float4*>(xn + (size_t)c * L_SEQ + l0 + l4);
    ushort4 u;
    u.x = f2bf(v.x); u.y = f2bf(v.y); u.z = f2bf(v.z); u.w = f2bf(v.w);
    *reinterpret_cast<ushort4*>(&xs[c * PADT + l4]) = u;
  }
  __syncthreads();

  const int wv = t >> 6;
  const int lane = t & 63;
  const int r16 = lane & 15;
  const int kg = lane >> 4;
  f32x4 acc[8];
#pragma unroll
  for (int ot = 0; ot < 8; ++ot) acc[ot] = (f32x4){0.f, 0.f, 0.f, 0.f};

#pragma unroll
  for (int ks = 0; ks < 4; ++ks) {
    bf16x8 a;
#pragma unroll
    for (int j = 0; j < 8; ++j)
      a[j] = (short)xs[(ks * 32 + kg * 8 + j) * PADT + wv * 16 + r16];
#pragma unroll
    for (int ot = 0; ot < 8; ++ot) {
      bf16x8 b = *reinterpret_cast<const bf16x8*>(&was[(ot * 16 + r16) * PADW + ks * 32 + kg * 8]);
      acc[ot] = __builtin_amdgcn_mfma_f32_16x16x32_bf16(a, b, acc[ot], 0, 0, 0);
    }
  }
#pragma unroll
  for (int ot = 0; ot < 8; ++ot) {
    float bav = ba[ot * 16 + r16];
    ushort4 u;
    u.x = f2bf(acc[ot][0] + bav);
    u.y = f2bf(acc[ot][1] + bav);
    u.z = f2bf(acc[ot][2] + bav);
    u.w = f2bf(acc[ot][3] + bav);
    size_t idx = (((size_t)n * H_HEADS + ot) * HD + r16) * L_SEQ + l0 + wv * 16 + kg * 4;
    *reinterpret_cast<ushort4*>(&w2[idx]) = u;
  }
}

// ---------------- K2: per-(n,h) scan; 1024 threads, 64 segs x 25, parity-uniform waves ----------------
__global__ __launch_bounds__(1024, 4) void k_scan(const unsigned short* __restrict__ w2,
                                                  unsigned short* __restrict__ y2,
                                                  const float* __restrict__ temp,
                                                  const float* __restrict__ dbias) {
  __shared__ float tmp_l[L_SEQ];          // e = exp(tmp - M), unnormalized
  __shared__ float cbufw[16 * 340];       // per-wave scratch: [wave][sl*5+j][17]
  __shared__ float stot[SEGN][17];
  __shared__ float pi_seg[SEGN];
  __shared__ float red[16];

  const int nh = blockIdx.x;
  const int h = nh & 7;
  const int t = threadIdx.x;
  const int d = t & 15;
  const int lane = t & 63;
  const int wv = t >> 6;                  // 0..15
  const int OFF = wv >> 3;                // parity, wave-uniform
  const int wl = wv & 7;
  const int sl = lane >> 4;               // local seg within wave (0..3)
  const int seg = 8 * wl + 2 * sl + OFF;  // 0..63, wave-uniform parity
  const int l0 = seg * SEGL;
  const int g0 = (nh * HD + d) * L_SEQ + l0;
  const float tscale = temp[h];
  const float db16 = 16.f * dbias[h];
  // Sigma_d wsq/denom in (0,16], ==16 at l=0 -> exact-at-l0 upper bound on tmp.
  const float M = fmaxf((16.f + db16) * tscale, db16 * tscale);

  // ---- load 13 dwords covering the 25-elem slice (g0-OFF is even) ----
  unsigned int dw[13];
  {
    const unsigned int* src = reinterpret_cast<const unsigned int*>(w2 + (g0 - OFF));
#pragma unroll
    for (int ii = 0; ii < 13; ++ii) dw[ii] = src[ii];
  }
  // ---- unpack to 25 statically-indexed floats (parity branch is wave-uniform) ----
  float v[SEGL];
  if (OFF == 0) {
#pragma unroll
    for (int i = 0; i < SEGL; ++i)
      v[i] = (i & 1) ? bfhi(dw[i >> 1]) : bflo(dw[i >> 1]);
  } else {
#pragma unroll
    for (int i = 0; i < SEGL; ++i)
      v[i] = ((i + 1) & 1) ? bfhi(dw[(i + 1) >> 1]) : bflo(dw[(i + 1) >> 1]);
  }

  // ---- sweep 1a: per-segment sum of w^2 per channel ----
  float tot = 0.f;
#pragma unroll
  for (int i = 0; i < SEGL; ++i) tot += v[i] * v[i];
  stot[seg][d] = tot;
  __syncthreads();                        // barrier 1
  float off = 0.f;
#pragma unroll
  for (int s = 0; s < SEGN; ++s) { float q = stot[s][d]; if (s < seg) off += q; }

  // ---- sweep 1b: cumsum -> wsq/denom; per-wave transpose-sum in chunks of 5; fused exp ----
  float* cw = &cbufw[wv * 340];
  const int rsl = lane / 5;               // reader mapping (lane < 20)
  const int rj = lane - rsl * 5;
  const int rseg = 8 * wl + 2 * rsl + OFF;
  float run = off;
  float sAcc = 0.f;
#pragma unroll
  for (int i0 = 0; i0 < SEGL; i0 += 5) {
#pragma unroll
    for (int j = 0; j < 5; ++j) {
      float vv = v[i0 + j];
      float wsq = vv * vv;
      run += wsq;
      cw[(sl * 5 + j) * 17 + d] = __fdividef(wsq, fmaxf(run, 1e-12f));
    }
    __builtin_amdgcn_wave_barrier();
    if (lane < 20) {
      float a = 0.f;
#pragma unroll
      for (int dd = 0; dd < 16; ++dd) a += cw[(rsl * 5 + rj) * 17 + dd];
      float e = __expf((a + db16) * tscale - M);
      tmp_l[rseg * SEGL + i0 + rj] = e;
      sAcc += e;
    }
    __builtin_amdgcn_wave_barrier();
  }
  // block-reduce S (only lanes<20 hold partials; others contribute 0)
#pragma unroll
  for (int mask = 32; mask; mask >>= 1) sAcc += __shfl_xor(sAcc, mask);
  if (lane == 0) red[wv] = sAcc;
  __syncthreads();                        // barrier 2: tmp_l + red visible; stot reusable
  float S = 0.f;
#pragma unroll
  for (int i2 = 0; i2 < 16; ++i2) S += red[i2];
  const float ninvS = -1.0f / S;
  const float epsS = 1e-8f * S;

  // ---- sweep 2a: per-segment totals of wsq*e (per d) and e ----
  float wp_tot = 0.f, pi_tot = 0.f;
#pragma unroll
  for (int i = 0; i < SEGL; ++i) {
    float e = tmp_l[l0 + i];
    wp_tot += v[i] * v[i] * e;
    pi_tot += e;
  }
  stot[seg][d] = wp_tot;
  if (d == 0) pi_seg[seg] = pi_tot;
  __syncthreads();                        // barrier 3
  float wp_off = 0.f, pi_off = 0.f;
#pragma unroll
  for (int s2 = 0; s2 < SEGN; ++s2) {
    float vw = stot[s2][d];
    float vq = pi_seg[s2];
    if (s2 < seg) { wp_off += vw; pi_off += vq; }
  }

  // ---- sweep 2b: unnormalized running cumsums -> y in place of v ----
  {
    float run_wp = wp_off, run_pi = pi_off;
#pragma unroll
    for (int i = 0; i < SEGL; ++i) {
      float e = tmp_l[l0 + i];
      run_pi += e;
      float wsq = v[i] * v[i];
      run_wp += wsq * e;
      float dn = run_pi + epsS;
      v[i] = (v[i] * e) * __fdividef(dn, dn + run_wp) * ninvS;
    }
  }

  // ---- pack + store (parity branch is wave-uniform) ----
  if (OFF == 0) {
    unsigned int* dst = reinterpret_cast<unsigned int*>(y2 + g0);
#pragma unroll
    for (int ii = 0; ii < 12; ++ii) dst[ii] = pk(v[2 * ii], v[2 * ii + 1]);
    y2[g0 + 24] = f2bf(v[24]);
  } else {
    y2[g0] = f2bf(v[0]);
    unsigned int* dst = reinterpret_cast<unsigned int*>(y2 + g0 + 1);
#pragma unroll
    for (int ii = 0; ii < 12; ++ii) dst[ii] = pk(v[1 + 2 * ii], v[2 + 2 * ii]);
  }
}

// ---------------- K3: out = relu(Wp . y + bp + x)  (bf16 MFMA, y2 d-major) ----------------
__global__ __launch_bounds__(256) void k_gemm2(const unsigned short* __restrict__ y2,
                                               const float* __restrict__ Wp,
                                               const float* __restrict__ bp,
                                               const float* __restrict__ x,
                                               float* __restrict__ out) {
  __shared__ unsigned short wps[128 * PADW];   // [o][c] rows
  __shared__ unsigned short ys[128 * PADT];    // [c][l] natural layout
  const int n = blockIdx.y;
  const int l0 = blockIdx.x * 64;
  const int t = threadIdx.x;

#pragma unroll
  for (int it = 0; it < 16; ++it) {
    int pos = it * 256 + t;
    int o = pos >> 5;
    int c4 = (pos & 31) << 2;
    float4 v = *reinterpret_cast<const float4*>(Wp + o * C_CH + c4);
    ushort4 u;
    u.x = f2bf(v.x); u.y = f2bf(v.y); u.z = f2bf(v.z); u.w = f2bf(v.w);
    *reinterpret_cast<ushort4*>(&wps[o * PADW + c4]) = u;
  }
#pragma unroll
  for (int it = 0; it < 4; ++it) {
    int pos = it * 256 + t;          // 0..1023
    int c = pos >> 3;
    int l8 = (pos & 7) << 3;
    uint4 v = *reinterpret_cast<const uint4*>(y2 + ((size_t)n * C_CH + c) * L_SEQ + l0 + l8);
    *reinterpret_cast<uint4*>(&ys[c * PADT + l8]) = v;
  }
  __syncthreads();

  const int wv = t >> 6;
  const int lane = t & 63;
  const int r16 = lane & 15;
  const int kg = lane >> 4;
  f32x4 acc[8];
#pragma unroll
  for (int ot = 0; ot < 8; ++ot) acc[ot] = (f32x4){0.f, 0.f, 0.f, 0.f};

#pragma unroll
  for (int ks = 0; ks < 4; ++ks) {
    bf16x8 b;
#pragma unroll
    for (int j = 0; j < 8; ++j)
      b[j] = (short)ys[(ks * 32 + kg * 8 + j) * PADT + wv * 16 + r16];
#pragma unroll
    for (int ot = 0; ot < 8; ++ot) {
      bf16x8 a = *reinterpret_cast<const bf16x8*>(&wps[(ot * 16 + r16) * PADW + ks * 32 + kg * 8]);
      acc[ot] = __builtin_amdgcn_mfma_f32_16x16x32_bf16(a, b, acc[ot], 0, 0, 0);
    }
  }
  const int gl = l0 + wv * 16 + r16;
#pragma unroll
  for (int ot = 0; ot < 8; ++ot) {
#pragma unroll
    for (int i = 0; i < 4; ++i) {
      int o = ot * 16 + kg * 4 + i;
      size_t idx = (size_t)n * (C_CH * L_SEQ) + (size_t)o * L_SEQ + gl;
      float r = acc[ot][i] + bp[o] + x[idx];
      out[idx] = fmaxf(r, 0.f);
    }
  }
}

extern "C" void kernel_launch(void* const* d_in, const int* in_sizes, int n_in,
                              void* d_out, int out_size, void* d_ws, size_t ws_size,
                              hipStream_t stream) {
  const float* x     = (const float*)d_in[0];
  const float* Wa    = (const float*)d_in[1];
  const float* ba    = (const float*)d_in[2];
  const float* Wp    = (const float*)d_in[3];
  const float* bp    = (const float*)d_in[4];
  const float* temp  = (const float*)d_in[5];
  const float* dbias = (const float*)d_in[6];
  float* out = (float*)d_out;

  unsigned short* w2 = (unsigned short*)d_ws;                       // 26.2 MB
  unsigned short* y2 = w2 + (size_t)N_S * H_HEADS * L_SEQ * HD;     // 26.2 MB

  k_gemm1<<<dim3(L_SEQ / 64, N_S), 256, 0, stream>>>(x, Wa, ba, w2);
  k_scan<<<N_S * H_HEADS, 1024, 0, stream>>>(w2, y2, temp, dbias);
  k_gemm2<<<dim3(L_SEQ / 64, N_S), 256, 0, stream>>>(y2, Wp, bp, x, out);
}

// Round 8
// 80.097 us; speedup vs baseline: 1.0658x; 1.0658x over previous
//
#include <hip/hip_runtime.h>
#include <hip/hip_bf16.h>

#define N_S     64
#define C_CH    128
#define L_SEQ   1600
#define H_HEADS 8
#define HD      16
#define SEGN    64    // segments per (n,h)
#define SEGL    25    // elements per segment (64*25 = 1600)
#define PADW    136   // weight LDS row pad (bf16 elems)
#define PADT    72    // x/y tile LDS row pad (bf16 elems)

typedef __attribute__((ext_vector_type(8))) short bf16x8;
typedef __attribute__((ext_vector_type(4))) float f32x4;

__device__ inline unsigned short f2bf(float f) {
  return __builtin_bit_cast(unsigned short, __float2bfloat16(f));
}
__device__ inline float bflo(unsigned int u) { return __builtin_bit_cast(float, u << 16); }
__device__ inline float bfhi(unsigned int u) { return __builtin_bit_cast(float, u & 0xffff0000u); }
__device__ inline unsigned int pk(float a, float b) {
  return (unsigned int)f2bf(a) | ((unsigned int)f2bf(b) << 16);
}

// ---------------- K1: w2[n, c=16h+d, l] (bf16) = sum_c x[n,c,l]*Wa[16h+d][c] + ba ----------------
__global__ __launch_bounds__(256) void k_gemm1(const float* __restrict__ x,
                                               const float* __restrict__ Wa,
                                               const float* __restrict__ ba,
                                               unsigned short* __restrict__ w2) {
  __shared__ unsigned short was[128 * PADW];   // [o][c] rows
  __shared__ unsigned short xs[128 * PADT];    // [c][l] natural layout
  const int n = blockIdx.y;
  const int l0 = blockIdx.x * 64;
  const int t = threadIdx.x;
  const float* xn = x + (size_t)n * (C_CH * L_SEQ);

#pragma unroll
  for (int it = 0; it < 16; ++it) {
    int pos = it * 256 + t;
    int o = pos >> 5;
    int c4 = (pos & 31) << 2;
    float4 v = *reinterpret_cast<const float4*>(Wa + o * C_CH + c4);
    ushort4 u;
    u.x = f2bf(v.x); u.y = f2bf(v.y); u.z = f2bf(v.z); u.w = f2bf(v.w);
    *reinterpret_cast<ushort4*>(&was[o * PADW + c4]) = u;
  }
#pragma unroll
  for (int it = 0; it < 8; ++it) {
    int pos = it * 256 + t;
    int c = pos >> 4;
    int l4 = (pos & 15) << 2;
    float4 v = *reinterpret_cast<const float4*>(xn + (size_t)c * L_SEQ + l0 + l4);
    ushort4 u;
    u.x = f2bf(v.x); u.y = f2bf(v.y); u.z = f2bf(v.z); u.w = f2bf(v.w);
    *reinterpret_cast<ushort4*>(&xs[c * PADT + l4]) = u;
  }
  __syncthreads();

  const int wv = t >> 6;
  const int lane = t & 63;
  const int r16 = lane & 15;
  const int kg = lane >> 4;
  f32x4 acc[8];
#pragma unroll
  for (int ot = 0; ot < 8; ++ot) acc[ot] = (f32x4){0.f, 0.f, 0.f, 0.f};

#pragma unroll
  for (int ks = 0; ks < 4; ++ks) {
    bf16x8 a;
#pragma unroll
    for (int j = 0; j < 8; ++j)
      a[j] = (short)xs[(ks * 32 + kg * 8 + j) * PADT + wv * 16 + r16];
#pragma unroll
    for (int ot = 0; ot < 8; ++ot) {
      bf16x8 b = *reinterpret_cast<const bf16x8*>(&was[(ot * 16 + r16) * PADW + ks * 32 + kg * 8]);
      acc[ot] = __builtin_amdgcn_mfma_f32_16x16x32_bf16(a, b, acc[ot], 0, 0, 0);
    }
  }
#pragma unroll
  for (int ot = 0; ot < 8; ++ot) {
    float bav = ba[ot * 16 + r16];
    ushort4 u;
    u.x = f2bf(acc[ot][0] + bav);
    u.y = f2bf(acc[ot][1] + bav);
    u.z = f2bf(acc[ot][2] + bav);
    u.w = f2bf(acc[ot][3] + bav);
    size_t idx = (((size_t)n * H_HEADS + ot) * HD + r16) * L_SEQ + l0 + wv * 16 + kg * 4;
    *reinterpret_cast<ushort4*>(&w2[idx]) = u;
  }
}

// ---------------- K2: per-(n,h) scan; parallel cross-segment prefix via shfl_up ----------------
__global__ __launch_bounds__(1024, 4) void k_scan(const unsigned short* __restrict__ w2,
                                                  unsigned short* __restrict__ y2,
                                                  const float* __restrict__ temp,
                                                  const float* __restrict__ dbias) {
  __shared__ float tmp_l[L_SEQ];          // e = exp(tmp - M), unnormalized
  __shared__ float cbufw[16 * 340];       // per-wave scratch: [wave][sl*5+j][17]
  __shared__ float stot[SEGN][17];        // per-seg totals; col 16 = pi column (sweep 2)
  __shared__ float red[16];

  const int nh = blockIdx.x;
  const int h = nh & 7;
  const int t = threadIdx.x;
  const int d = t & 15;
  const int lane = t & 63;
  const int wv = t >> 6;                  // 0..15
  const int OFF = wv >> 3;                // parity, wave-uniform
  const int wl = wv & 7;
  const int sl = lane >> 4;               // local seg within wave (0..3)
  const int seg = 8 * wl + 2 * sl + OFF;  // 0..63, wave-uniform parity
  const int l0 = seg * SEGL;
  const int g0 = (nh * HD + d) * L_SEQ + l0;
  const float tscale = temp[h];
  const float db16 = 16.f * dbias[h];
  // Sigma_d wsq/denom in (0,16], ==16 at l=0 -> exact-at-l0 upper bound on tmp.
  const float M = fmaxf((16.f + db16) * tscale, db16 * tscale);

  // ---- load 13 dwords covering the 25-elem slice (g0-OFF is even) ----
  unsigned int dw[13];
  {
    const unsigned int* src = reinterpret_cast<const unsigned int*>(w2 + (g0 - OFF));
#pragma unroll
    for (int ii = 0; ii < 13; ++ii) dw[ii] = src[ii];
  }
  // ---- unpack to 25 statically-indexed floats (parity branch is wave-uniform) ----
  float v[SEGL];
  if (OFF == 0) {
#pragma unroll
    for (int i = 0; i < SEGL; ++i)
      v[i] = (i & 1) ? bfhi(dw[i >> 1]) : bflo(dw[i >> 1]);
  } else {
#pragma unroll
    for (int i = 0; i < SEGL; ++i)
      v[i] = ((i + 1) & 1) ? bfhi(dw[(i + 1) >> 1]) : bflo(dw[(i + 1) >> 1]);
  }

  // ---- sweep 1a: per-segment sum of w^2 per channel ----
  float tot = 0.f;
#pragma unroll
  for (int i = 0; i < SEGL; ++i) tot += v[i] * v[i];
  stot[seg][d] = tot;
  __syncthreads();                        // B1
  // parallel prefix: wave w scans column d=w over 64 segments
  {
    float val = stot[lane][wv];
#pragma unroll
    for (int sh = 1; sh < 64; sh <<= 1) {
      float nv = __shfl_up(val, sh);
      if (lane >= sh) val += nv;
    }
    stot[lane][wv] = val;                 // inclusive prefix
  }
  __syncthreads();                        // B2
  const float off = stot[seg][d] - tot;   // exclusive prefix

  // ---- sweep 1b: cumsum -> wsq/denom; per-wave transpose-sum in chunks of 5; fused exp ----
  float* cw = &cbufw[wv * 340];
  const int rsl = lane / 5;               // reader mapping (lane < 20)
  const int rj = lane - rsl * 5;
  const int rseg = 8 * wl + 2 * rsl + OFF;
  float run = off;
  float sAcc = 0.f;
#pragma unroll
  for (int i0 = 0; i0 < SEGL; i0 += 5) {
#pragma unroll
    for (int j = 0; j < 5; ++j) {
      float vv = v[i0 + j];
      float wsq = vv * vv;
      run += wsq;
      cw[(sl * 5 + j) * 17 + d] = __fdividef(wsq, fmaxf(run, 1e-12f));
    }
    __builtin_amdgcn_wave_barrier();
    if (lane < 20) {
      float a = 0.f;
#pragma unroll
      for (int dd = 0; dd < 16; ++dd) a += cw[(rsl * 5 + rj) * 17 + dd];
      float e = __expf((a + db16) * tscale - M);
      tmp_l[rseg * SEGL + i0 + rj] = e;
      sAcc += e;
    }
    __builtin_amdgcn_wave_barrier();
  }
  // block-reduce S (only lanes<20 hold partials; others contribute 0)
#pragma unroll
  for (int mask = 32; mask; mask >>= 1) sAcc += __shfl_xor(sAcc, mask);
  if (lane == 0) red[wv] = sAcc;
  __syncthreads();                        // B3: tmp_l + red visible
  float S = 0.f;
#pragma unroll
  for (int i2 = 0; i2 < 16; ++i2) S += red[i2];
  const float ninvS = -1.0f / S;
  const float epsS = 1e-8f * S;

  // ---- sweep 2a: per-segment totals of wsq*e (per d) and e ----
  float wp_tot = 0.f, pi_tot = 0.f;
#pragma unroll
  for (int i = 0; i < SEGL; ++i) {
    float e = tmp_l[l0 + i];
    wp_tot += v[i] * v[i] * e;
    pi_tot += e;
  }
  stot[seg][d] = wp_tot;
  if (d == 0) stot[seg][16] = pi_tot;
  __syncthreads();                        // B4
  // parallel prefix over both wp columns (waves 0..15) and pi column (wave 0)
  {
    float val = stot[lane][wv];
#pragma unroll
    for (int sh = 1; sh < 64; sh <<= 1) {
      float nv = __shfl_up(val, sh);
      if (lane >= sh) val += nv;
    }
    stot[lane][wv] = val;
    if (wv == 0) {
      float val2 = stot[lane][16];
#pragma unroll
      for (int sh = 1; sh < 64; sh <<= 1) {
        float nv = __shfl_up(val2, sh);
        if (lane >= sh) val2 += nv;
      }
      stot[lane][16] = val2;
    }
  }
  __syncthreads();                        // B5
  const float wp_off = stot[seg][d] - wp_tot;
  const float pi_off = stot[seg][16] - pi_tot;

  // ---- sweep 2b: unnormalized running cumsums -> y in place of v ----
  {
    float run_wp = wp_off, run_pi = pi_off;
#pragma unroll
    for (int i = 0; i < SEGL; ++i) {
      float e = tmp_l[l0 + i];
      run_pi += e;
      float wsq = v[i] * v[i];
      run_wp += wsq * e;
      float dn = run_pi + epsS;
      v[i] = (v[i] * e) * __fdividef(dn, dn + run_wp) * ninvS;
    }
  }

  // ---- pack + store (parity branch is wave-uniform) ----
  if (OFF == 0) {
    unsigned int* dst = reinterpret_cast<unsigned int*>(y2 + g0);
#pragma unroll
    for (int ii = 0; ii < 12; ++ii) dst[ii] = pk(v[2 * ii], v[2 * ii + 1]);
    y2[g0 + 24] = f2bf(v[24]);
  } else {
    y2[g0] = f2bf(v[0]);
    unsigned int* dst = reinterpret_cast<unsigned int*>(y2 + g0 + 1);
#pragma unroll
    for (int ii = 0; ii < 12; ++ii) dst[ii] = pk(v[1 + 2 * ii], v[2 + 2 * ii]);
  }
}

// ---------------- K3: out = relu(Wp . y + bp + x)  (bf16 MFMA, y2 d-major) ----------------
__global__ __launch_bounds__(256) void k_gemm2(const unsigned short* __restrict__ y2,
                                               const float* __restrict__ Wp,
                                               const float* __restrict__ bp,
                                               const float* __restrict__ x,
                                               float* __restrict__ out) {
  __shared__ unsigned short wps[128 * PADW];   // [o][c] rows
  __shared__ unsigned short ys[128 * PADT];    // [c][l] natural layout
  const int n = blockIdx.y;
  const int l0 = blockIdx.x * 64;
  const int t = threadIdx.x;

#pragma unroll
  for (int it = 0; it < 16; ++it) {
    int pos = it * 256 + t;
    int o = pos >> 5;
    int c4 = (pos & 31) << 2;
    float4 v = *reinterpret_cast<const float4*>(Wp + o * C_CH + c4);
    ushort4 u;
    u.x = f2bf(v.x); u.y = f2bf(v.y); u.z = f2bf(v.z); u.w = f2bf(v.w);
    *reinterpret_cast<ushort4*>(&wps[o * PADW + c4]) = u;
  }
#pragma unroll
  for (int it = 0; it < 4; ++it) {
    int pos = it * 256 + t;          // 0..1023
    int c = pos >> 3;
    int l8 = (pos & 7) << 3;
    uint4 v = *reinterpret_cast<const uint4*>(y2 + ((size_t)n * C_CH + c) * L_SEQ + l0 + l8);
    *reinterpret_cast<uint4*>(&ys[c * PADT + l8]) = v;
  }
  __syncthreads();

  const int wv = t >> 6;
  const int lane = t & 63;
  const int r16 = lane & 15;
  const int kg = lane >> 4;
  f32x4 acc[8];
#pragma unroll
  for (int ot = 0; ot < 8; ++ot) acc[ot] = (f32x4){0.f, 0.f, 0.f, 0.f};

#pragma unroll
  for (int ks = 0; ks < 4; ++ks) {
    bf16x8 b;
#pragma unroll
    for (int j = 0; j < 8; ++j)
      b[j] = (short)ys[(ks * 32 + kg * 8 + j) * PADT + wv * 16 + r16];
#pragma unroll
    for (int ot = 0; ot < 8; ++ot) {
      bf16x8 a = *reinterpret_cast<const bf16x8*>(&wps[(ot * 16 + r16) * PADW + ks * 32 + kg * 8]);
      acc[ot] = __builtin_amdgcn_mfma_f32_16x16x32_bf16(a, b, acc[ot], 0, 0, 0);
    }
  }
  const int gl = l0 + wv * 16 + r16;
#pragma unroll
  for (int ot = 0; ot < 8; ++ot) {
#pragma unroll
    for (int i = 0; i < 4; ++i) {
      int o = ot * 16 + kg * 4 + i;
      size_t idx = (size_t)n * (C_CH * L_SEQ) + (size_t)o * L_SEQ + gl;
      float r = acc[ot][i] + bp[o] + x[idx];
      out[idx] = fmaxf(r, 0.f);
    }
  }
}

extern "C" void kernel_launch(void* const* d_in, const int* in_sizes, int n_in,
                              void* d_out, int out_size, void* d_ws, size_t ws_size,
                              hipStream_t stream) {
  const float* x     = (const float*)d_in[0];
  const float* Wa    = (const float*)d_in[1];
  const float* ba    = (const float*)d_in[2];
  const float* Wp    = (const float*)d_in[3];
  const float* bp    = (const float*)d_in[4];
  const float* temp  = (const float*)d_in[5];
  const float* dbias = (const float*)d_in[6];
  float* out = (float*)d_out;

  unsigned short* w2 = (unsigned short*)d_ws;                       // 26.2 MB
  unsigned short* y2 = w2 + (size_t)N_S * H_HEADS * L_SEQ * HD;     // 26.2 MB

  k_gemm1<<<dim3(L_SEQ / 64, N_S), 256, 0, stream>>>(x, Wa, ba, w2);
  k_scan<<<N_S * H_HEADS, 1024, 0, stream>>>(w2, y2, temp, dbias);
  k_gemm2<<<dim3(L_SEQ / 64, N_S), 256, 0, stream>>>(y2, Wp, bp, x, out);
}

// Round 9
// 76.853 us; speedup vs baseline: 1.1108x; 1.0422x over previous
//
#include <hip/hip_runtime.h>
#include <hip/hip_bf16.h>

#define N_S     64
#define C_CH    128
#define L_SEQ   1600
#define H_HEADS 8
#define HD      16
#define SEGN    32    // segments per (n,h)
#define SEGL    50    // elements per segment (32*50 = 1600)
#define PADW    136   // weight LDS row pad (bf16 elems)
#define PADT    72    // x/y tile LDS row pad (bf16 elems)

typedef __attribute__((ext_vector_type(8))) short bf16x8;
typedef __attribute__((ext_vector_type(4))) float f32x4;

__device__ inline unsigned short f2bf(float f) {
  return __builtin_bit_cast(unsigned short, __float2bfloat16(f));
}
__device__ inline float bflo(unsigned int u) { return __builtin_bit_cast(float, u << 16); }
__device__ inline float bfhi(unsigned int u) { return __builtin_bit_cast(float, u & 0xffff0000u); }
__device__ inline unsigned int pk(float a, float b) {
  return (unsigned int)f2bf(a) | ((unsigned int)f2bf(b) << 16);
}

// x + row_ror<C>(x): DPP row (16 lanes) rotate-add; 4 steps = full 16-lane sum.
template <int CTRL>
__device__ inline float dppadd(float x) {
  int r = __builtin_amdgcn_update_dpp(0, __builtin_bit_cast(int, x), CTRL, 0xF, 0xF, true);
  return x + __builtin_bit_cast(float, r);
}

// ---------------- K1: w2[n, c=16h+d, l] (bf16) = sum_c x[n,c,l]*Wa[16h+d][c] + ba ----------------
__global__ __launch_bounds__(256) void k_gemm1(const float* __restrict__ x,
                                               const float* __restrict__ Wa,
                                               const float* __restrict__ ba,
                                               unsigned short* __restrict__ w2) {
  __shared__ unsigned short was[128 * PADW];   // [o][c] rows
  __shared__ unsigned short xs[128 * PADT];    // [c][l] natural layout
  const int n = blockIdx.y;
  const int l0 = blockIdx.x * 64;
  const int t = threadIdx.x;
  const float* xn = x + (size_t)n * (C_CH * L_SEQ);

#pragma unroll
  for (int it = 0; it < 16; ++it) {
    int pos = it * 256 + t;
    int o = pos >> 5;
    int c4 = (pos & 31) << 2;
    float4 v = *reinterpret_cast<const float4*>(Wa + o * C_CH + c4);
    ushort4 u;
    u.x = f2bf(v.x); u.y = f2bf(v.y); u.z = f2bf(v.z); u.w = f2bf(v.w);
    *reinterpret_cast<ushort4*>(&was[o * PADW + c4]) = u;
  }
#pragma unroll
  for (int it = 0; it < 8; ++it) {
    int pos = it * 256 + t;
    int c = pos >> 4;
    int l4 = (pos & 15) << 2;
    float4 v = *reinterpret_cast<const float4*>(xn + (size_t)c * L_SEQ + l0 + l4);
    ushort4 u;
    u.x = f2bf(v.x); u.y = f2bf(v.y); u.z = f2bf(v.z); u.w = f2bf(v.w);
    *reinterpret_cast<ushort4*>(&xs[c * PADT + l4]) = u;
  }
  __syncthreads();

  const int wv = t >> 6;
  const int lane = t & 63;
  const int r16 = lane & 15;
  const int kg = lane >> 4;
  f32x4 acc[8];
#pragma unroll
  for (int ot = 0; ot < 8; ++ot) acc[ot] = (f32x4){0.f, 0.f, 0.f, 0.f};

#pragma unroll
  for (int ks = 0; ks < 4; ++ks) {
    bf16x8 a;
#pragma unroll
    for (int j = 0; j < 8; ++j)
      a[j] = (short)xs[(ks * 32 + kg * 8 + j) * PADT + wv * 16 + r16];
#pragma unroll
    for (int ot = 0; ot < 8; ++ot) {
      bf16x8 b = *reinterpret_cast<const bf16x8*>(&was[(ot * 16 + r16) * PADW + ks * 32 + kg * 8]);
      acc[ot] = __builtin_amdgcn_mfma_f32_16x16x32_bf16(a, b, acc[ot], 0, 0, 0);
    }
  }
#pragma unroll
  for (int ot = 0; ot < 8; ++ot) {
    float bav = ba[ot * 16 + r16];
    ushort4 u;
    u.x = f2bf(acc[ot][0] + bav);
    u.y = f2bf(acc[ot][1] + bav);
    u.z = f2bf(acc[ot][2] + bav);
    u.w = f2bf(acc[ot][3] + bav);
    size_t idx = (((size_t)n * H_HEADS + ot) * HD + r16) * L_SEQ + l0 + wv * 16 + kg * 4;
    *reinterpret_cast<ushort4*>(&w2[idx]) = u;
  }
}

// ---------------- K2: per-(n,h) scan; DPP row-sum, register e, LDS only for prefix ----------------
__global__ __launch_bounds__(512, 4) void k_scan(const unsigned short* __restrict__ w2,
                                                 unsigned short* __restrict__ y2,
                                                 const float* __restrict__ temp,
                                                 const float* __restrict__ dbias) {
  __shared__ float stot[SEGN][17];        // per-seg totals; col 16 = pi column (sweep 2)
  __shared__ float red[8];

  const int nh = blockIdx.x;
  const int h = nh & 7;
  const int t = threadIdx.x;
  const int d = t & 15;
  const int lane = t & 63;
  const int wv = t >> 6;                  // 0..7
  const int seg = t >> 4;                 // 0..31
  const size_t base = ((size_t)nh * HD + d) * L_SEQ + seg * SEGL;
  const float tscale = temp[h];
  const float db16 = 16.f * dbias[h];
  // Sigma_d wsq/denom in (0,16], ==16 at l=0 -> exact-at-l0 upper bound on tmp.
  const float M = fmaxf((16.f + db16) * tscale, db16 * tscale);

  // ---- load contiguous 50-elem bf16 slice (25 packed dwords) ----
  unsigned int vp[25];
  {
    const unsigned int* src = reinterpret_cast<const unsigned int*>(w2 + base);
#pragma unroll
    for (int ii = 0; ii < 25; ++ii) vp[ii] = src[ii];
  }

  // ---- sweep 1a: per-segment sum of w^2 per channel ----
  float tot = 0.f;
#pragma unroll
  for (int ii = 0; ii < 25; ++ii) {
    float a = bflo(vp[ii]), b = bfhi(vp[ii]);
    tot += a * a + b * b;
  }
  stot[seg][d] = tot;
  __syncthreads();                        // B1
  // parallel prefix: wave w scans cols w and w+8 over 32 segments (lanes 0..31)
#pragma unroll
  for (int it = 0; it < 2; ++it) {
    int col = wv + it * 8;
    float val = (lane < 32) ? stot[lane][col] : 0.f;
#pragma unroll
    for (int sh = 1; sh < 32; sh <<= 1) {
      float nv = __shfl_up(val, sh);
      if (lane >= sh) val += nv;
    }
    if (lane < 32) stot[lane][col] = val;
  }
  __syncthreads();                        // B2
  const float off = stot[seg][d] - tot;   // exclusive prefix

  // ---- sweep 1b: cumsum -> wsq/denom; DPP 16-lane row-sum; fused exp + 2a totals ----
  unsigned int ep[25];
  float run = off;
  float sAcc = 0.f, wpAcc = 0.f;
  float eprev = 0.f;
#pragma unroll
  for (int i = 0; i < SEGL; ++i) {
    float v = (i & 1) ? bfhi(vp[i >> 1]) : bflo(vp[i >> 1]);
    float wsq = v * v;
    run += wsq;
    float c = __fdividef(wsq, fmaxf(run, 1e-12f));
    c = dppadd<0x128>(c);                 // row_ror:8
    c = dppadd<0x124>(c);                 // row_ror:4
    c = dppadd<0x122>(c);                 // row_ror:2
    c = dppadd<0x121>(c);                 // row_ror:1 -> full 16-lane sum
    float e = __expf((c + db16) * tscale - M);
    sAcc += e;
    wpAcc = fmaf(wsq, e, wpAcc);
    if (i & 1) ep[i >> 1] = pk(eprev, e); else eprev = e;
  }
  // block-reduce S (each lane's sAcc counts its row's e once per d -> /16 at the end)
  {
    float s = sAcc;
#pragma unroll
    for (int mask = 32; mask; mask >>= 1) s += __shfl_xor(s, mask);
    if (lane == 0) red[wv] = s;
  }
  __syncthreads();                        // B3 (stot sweep-1 reads all done before here)
  float S16 = 0.f;
#pragma unroll
  for (int i2 = 0; i2 < 8; ++i2) S16 += red[i2];
  const float S = S16 * 0.0625f;
  const float ninvS = -1.0f / S;
  const float epsS = 1e-8f * S;

  // ---- sweep 2 prefix: per-seg wp (per d) and pi totals ----
  stot[seg][d] = wpAcc;
  if (d == 0) stot[seg][16] = sAcc;
  __syncthreads();                        // B4
#pragma unroll
  for (int it = 0; it < 2; ++it) {
    int col = wv + it * 8;
    float val = (lane < 32) ? stot[lane][col] : 0.f;
#pragma unroll
    for (int sh = 1; sh < 32; sh <<= 1) {
      float nv = __shfl_up(val, sh);
      if (lane >= sh) val += nv;
    }
    if (lane < 32) stot[lane][col] = val;
  }
  if (wv == 0) {
    float val = (lane < 32) ? stot[lane][16] : 0.f;
#pragma unroll
    for (int sh = 1; sh < 32; sh <<= 1) {
      float nv = __shfl_up(val, sh);
      if (lane >= sh) val += nv;
    }
    if (lane < 32) stot[lane][16] = val;
  }
  __syncthreads();                        // B5
  const float wp_off = stot[seg][d] - wpAcc;
  const float pi_off = stot[seg][16] - sAcc;

  // ---- sweep 2b: unnormalized running cumsums -> y in place of vp ----
  {
    float run_wp = wp_off, run_pi = pi_off;
    float ylo = 0.f;
#pragma unroll
    for (int i = 0; i < SEGL; ++i) {
      float v = (i & 1) ? bfhi(vp[i >> 1]) : bflo(vp[i >> 1]);
      float e = (i & 1) ? bfhi(ep[i >> 1]) : bflo(ep[i >> 1]);
      run_pi += e;
      run_wp = fmaf(v * v, e, run_wp);
      float dn = run_pi + epsS;
      float y = (v * e) * __fdividef(dn, dn + run_wp) * ninvS;
      if (i & 1) vp[i >> 1] = pk(ylo, y); else ylo = y;
    }
  }
  {
    unsigned int* dst = reinterpret_cast<unsigned int*>(y2 + base);
#pragma unroll
    for (int ii = 0; ii < 25; ++ii) dst[ii] = vp[ii];
  }
}

// ---------------- K3: out = relu(Wp . y + bp + x)  (bf16 MFMA, y2 d-major) ----------------
__global__ __launch_bounds__(256) void k_gemm2(const unsigned short* __restrict__ y2,
                                               const float* __restrict__ Wp,
                                               const float* __restrict__ bp,
                                               const float* __restrict__ x,
                                               float* __restrict__ out) {
  __shared__ unsigned short wps[128 * PADW];   // [o][c] rows
  __shared__ unsigned short ys[128 * PADT];    // [c][l] natural layout
  const int n = blockIdx.y;
  const int l0 = blockIdx.x * 64;
  const int t = threadIdx.x;

#pragma unroll
  for (int it = 0; it < 16; ++it) {
    int pos = it * 256 + t;
    int o = pos >> 5;
    int c4 = (pos & 31) << 2;
    float4 v = *reinterpret_cast<const float4*>(Wp + o * C_CH + c4);
    ushort4 u;
    u.x = f2bf(v.x); u.y = f2bf(v.y); u.z = f2bf(v.z); u.w = f2bf(v.w);
    *reinterpret_cast<ushort4*>(&wps[o * PADW + c4]) = u;
  }
#pragma unroll
  for (int it = 0; it < 4; ++it) {
    int pos = it * 256 + t;          // 0..1023
    int c = pos >> 3;
    int l8 = (pos & 7) << 3;
    uint4 v = *reinterpret_cast<const uint4*>(y2 + ((size_t)n * C_CH + c) * L_SEQ + l0 + l8);
    *reinterpret_cast<uint4*>(&ys[c * PADT + l8]) = v;
  }
  __syncthreads();

  const int wv = t >> 6;
  const int lane = t & 63;
  const int r16 = lane & 15;
  const int kg = lane >> 4;
  f32x4 acc[8];
#pragma unroll
  for (int ot = 0; ot < 8; ++ot) acc[ot] = (f32x4){0.f, 0.f, 0.f, 0.f};

#pragma unroll
  for (int ks = 0; ks < 4; ++ks) {
    bf16x8 b;
#pragma unroll
    for (int j = 0; j < 8; ++j)
      b[j] = (short)ys[(ks * 32 + kg * 8 + j) * PADT + wv * 16 + r16];
#pragma unroll
    for (int ot = 0; ot < 8; ++ot) {
      bf16x8 a = *reinterpret_cast<const bf16x8*>(&wps[(ot * 16 + r16) * PADW + ks * 32 + kg * 8]);
      acc[ot] = __builtin_amdgcn_mfma_f32_16x16x32_bf16(a, b, acc[ot], 0, 0, 0);
    }
  }
  const int gl = l0 + wv * 16 + r16;
#pragma unroll
  for (int ot = 0; ot < 8; ++ot) {
#pragma unroll
    for (int i = 0; i < 4; ++i) {
      int o = ot * 16 + kg * 4 + i;
      size_t idx = (size_t)n * (C_CH * L_SEQ) + (size_t)o * L_SEQ + gl;
      float r = acc[ot][i] + bp[o] + x[idx];
      out[idx] = fmaxf(r, 0.f);
    }
  }
}

extern "C" void kernel_launch(void* const* d_in, const int* in_sizes, int n_in,
                              void* d_out, int out_size, void* d_ws, size_t ws_size,
                              hipStream_t stream) {
  const float* x     = (const float*)d_in[0];
  const float* Wa    = (const float*)d_in[1];
  const float* ba    = (const float*)d_in[2];
  const float* Wp    = (const float*)d_in[3];
  const float* bp    = (const float*)d_in[4];
  const float* temp  = (const float*)d_in[5];
  const float* dbias = (const float*)d_in[6];
  float* out = (float*)d_out;

  unsigned short* w2 = (unsigned short*)d_ws;                       // 26.2 MB
  unsigned short* y2 = w2 + (size_t)N_S * H_HEADS * L_SEQ * HD;     // 26.2 MB

  k_gemm1<<<dim3(L_SEQ / 64, N_S), 256, 0, stream>>>(x, Wa, ba, w2);
  k_scan<<<N_S * H_HEADS, 512, 0, stream>>>(w2, y2, temp, dbias);
  k_gemm2<<<dim3(L_SEQ / 64, N_S), 256, 0, stream>>>(y2, Wp, bp, x, out);
}